// Round 20
// baseline (211.243 us; speedup 1.0000x reference)
//
#include <hip/hip_runtime.h>
#include <hip/hip_bf16.h>

typedef __bf16 bf16;
typedef __bf16 bf16x8 __attribute__((ext_vector_type(8)));
typedef __bf16 bf16x4 __attribute__((ext_vector_type(4)));
typedef float f32x4 __attribute__((ext_vector_type(4)));

#define DEVFN static __device__ __forceinline__

DEVFN f32x4 mfma16(bf16x8 a, bf16x8 b, f32x4 c) {
  return __builtin_amdgcn_mfma_f32_16x16x32_bf16(a, b, c, 0, 0, 0);
}

DEVFN float hswish(float x) { return x * fminf(fmaxf(x + 3.f, 0.f), 6.f) * (1.f / 6.f); }
DEVFN float gelu_exact(float x) { return 0.5f * x * (1.f + erff(x * 0.70710678118654752f)); }
DEVFN float gelu_fast(float x) {
  float x2 = x * x;
  float w = -x * (2.3022227f + 0.10295342f * x2);
  float e = __builtin_amdgcn_exp2f(w);
  return x * __builtin_amdgcn_rcpf(1.f + e);
}

DEVFN unsigned packbf2(float lo, float hi) {
  union { bf16 h; unsigned short u; } a, b;
  a.h = (bf16)lo; b.h = (bf16)hi;
  return (unsigned)a.u | ((unsigned)b.u << 16);
}

// async global->LDS, 16B/lane: dest = wave-uniform base + lane*16.
DEVFN void async16(const void* g, void* l) {
  typedef __attribute__((address_space(3))) unsigned int lds_u32;
  typedef const __attribute__((address_space(1))) unsigned int glb_u32;
  __builtin_amdgcn_global_load_lds((glb_u32*)g, (lds_u32*)l, 16, 0, 0);
}

DEVFN int tmap(int dir, int b, int g, int m) {
  return dir == 0 ? (b * 4096 + g * 512 + m)
                  : (b * 4096 + (m & 63) * 64 + g * 8 + (m >> 6));
}

// ---------------- fused LayerNorm1 from f32 x -> xnb (bf16 LN out) ----------------
__global__ __launch_bounds__(256) void convx_ln(const float* __restrict__ src,
                                                const bf16* __restrict__ w,
                                                const bf16* __restrict__ b,
                                                bf16* __restrict__ xnb) {
  int tid = threadIdx.x, lane = tid & 63, wv = tid >> 6;
  long row = (long)blockIdx.x * 4 + wv;
  f32x4 xv = *(const f32x4*)(src + row * 256 + lane * 4);
  float s = xv[0] + xv[1] + xv[2] + xv[3];
#pragma unroll
  for (int m = 1; m < 64; m <<= 1) s += __shfl_xor(s, m);
  float mu = s * (1.f / 256.f);
  float q = 0.f;
#pragma unroll
  for (int i = 0; i < 4; i++) { float d = xv[i] - mu; q += d * d; }
#pragma unroll
  for (int m = 1; m < 64; m <<= 1) q += __shfl_xor(q, m);
  float r = rsqrtf(q * (1.f / 256.f) + 1e-5f);
  bf16x4 wv4 = *(const bf16x4*)(w + lane * 4);
  bf16x4 bv4 = *(const bf16x4*)(b + lane * 4);
  bf16x4 o;
#pragma unroll
  for (int i = 0; i < 4; i++) o[i] = (bf16)((xv[i] - mu) * r * (float)wv4[i] + (float)bv4[i]);
  *(bf16x4*)(xnb + row * 256 + lane * 4) = o;
}

// ---------------- convert all other inputs (f32 -> bf16, table-driven) ----------
struct ConvArgs { const float* s[24]; bf16* d[24]; };

__global__ __launch_bounds__(256) void convert_w(ConvArgs a) {
  static const int cum[25] = {0, 131072, 196608, 458752, 720896, 723200, 727808, 740608,
                              740864, 741120, 741632, 741888, 742144, 742400, 742656,
                              742912, 742928, 743184, 743200, 743456, 743712, 744736,
                              745248, 745760, 746016};
  static const int Kt[7] = {256, 256, 256, 1024, 256, 512, 512};
  static const int Nt[7] = {512, 256, 1024, 256, 9, 9, 25};
  int g = blockIdx.x * 256 + threadIdx.x;
  if (g >= 746016) return;
  int e = 0;
  while (g >= cum[e + 1]) e++;
  int i = g - cum[e];
  float v = a.s[e][i];
  int di = i;
  if (e < 7) di = (i % Nt[e]) * Kt[e] + i / Nt[e];
  a.d[e][di] = (bf16)v;
}

// ---------------- GEMM: C[MxN] = A[MxK] @ BT[NxK]^T + bias (+resid) ----------------
__global__ __launch_bounds__(256) void gemm_bt(const bf16* __restrict__ A,
                                               const bf16* __restrict__ BT,
                                               const bf16* __restrict__ bias,
                                               const bf16* __restrict__ resid,
                                               bf16* __restrict__ C,
                                               float* __restrict__ Cf,
                                               float* __restrict__ bnp,
                                               int M, int N, int K) {
  __shared__ __align__(16) bf16 Asl[2][128 * 32];
  __shared__ __align__(16) bf16 Bsl[2][128 * 32];
  const int tid = threadIdx.x;
  const int lane = tid & 63, wid = tid >> 6;
  const int rowBase = blockIdx.x * 128, colBase = blockIdx.y * 128;
  f32x4 acc[4][4] = {};
  const int e0 = wid * 1024 + lane * 8;
  const int e1 = e0 + 512;
  const int r0 = e0 >> 5, c0 = e0 & 31;
  const int r1 = e1 >> 5, c1 = e1 & 31;
  const bf16* Ab0 = A + (long)(rowBase + r0) * K + c0;
  const bf16* Ab1 = A + (long)(rowBase + r1) * K + c1;
  const bf16* Bb0 = BT + (long)(colBase + r0) * K + c0;
  const bf16* Bb1 = BT + (long)(colBase + r1) * K + c1;
  const int wr = (wid >> 1) * 64, wc = (wid & 1) * 64;
  const int fr = lane & 15, fk = (lane >> 4) * 8;
  const int nIt = K >> 5;
  async16(Ab0, &Asl[0][wid * 1024]);
  async16(Ab1, &Asl[0][wid * 1024 + 512]);
  async16(Bb0, &Bsl[0][wid * 1024]);
  async16(Bb1, &Bsl[0][wid * 1024 + 512]);
  for (int it = 0; it < nIt; ++it) {
    const int cur = it & 1;
    __syncthreads();
    if (it + 1 < nIt) {
      const int nxt = cur ^ 1;
      const int k1 = (it + 1) << 5;
      async16(Ab0 + k1, &Asl[nxt][wid * 1024]);
      async16(Ab1 + k1, &Asl[nxt][wid * 1024 + 512]);
      async16(Bb0 + k1, &Bsl[nxt][wid * 1024]);
      async16(Bb1 + k1, &Bsl[nxt][wid * 1024 + 512]);
    }
    bf16x8 af[4], bfv[4];
#pragma unroll
    for (int m = 0; m < 4; m++) af[m] = *(const bf16x8*)&Asl[cur][(wr + m * 16 + fr) * 32 + fk];
#pragma unroll
    for (int n = 0; n < 4; n++) bfv[n] = *(const bf16x8*)&Bsl[cur][(wc + n * 16 + fr) * 32 + fk];
#pragma unroll
    for (int m = 0; m < 4; m++)
#pragma unroll
      for (int n = 0; n < 4; n++) acc[m][n] = mfma16(af[m], bfv[n], acc[m][n]);
  }
  float cs[4] = {}, cq[4] = {};
#pragma unroll
  for (int m = 0; m < 4; m++) {
#pragma unroll
    for (int r = 0; r < 4; r++) {
      int row = rowBase + wr + m * 16 + (lane >> 4) * 4 + r;
#pragma unroll
      for (int n = 0; n < 4; n++) {
        int col = colBase + wc + n * 16 + fr;
        float v = acc[m][n][r] + (float)bias[col];
        if (resid) v += (float)resid[(long)row * N + col];
        if (bnp) { cs[n] += v; cq[n] += v * v; }
        if (Cf) Cf[(long)row * N + col] = v;
        else C[(long)row * N + col] = (bf16)v;
      }
    }
  }
  if (bnp) {
#pragma unroll
    for (int n = 0; n < 4; n++) {
      float s = cs[n], q = cq[n];
      s += __shfl_xor(s, 16); s += __shfl_xor(s, 32);
      q += __shfl_xor(q, 16); q += __shfl_xor(q, 32);
      if ((lane >> 4) == 0) {
        int slot = blockIdx.x * 2 + (wid >> 1);
        int gcol = colBase + wc + n * 16 + fr;
        bnp[slot * 256 + gcol] = s;
        bnp[65536 + slot * 256 + gcol] = q;
      }
    }
  }
}

// ---------------- depthwise 3x3 on hardswish(v), row-sliding channel-last ----------
__global__ __launch_bounds__(256) void dwconv_v(const bf16* __restrict__ qv,
                                                const bf16* __restrict__ wt,
                                                const bf16* __restrict__ cb,
                                                bf16* __restrict__ vconv) {
  int bx = blockIdx.x;
  int wh = bx & 1, h = (bx >> 1) & 63, b = bx >> 7;
  int tid = threadIdx.x;
  int c0 = (tid & 31) * 8;
  int w0 = wh * 32 + (tid >> 5) * 4;
  long base = (long)b * 4096;
  float acc[4][8];
#pragma unroll
  for (int q = 0; q < 8; q++) {
    float bv = (float)cb[c0 + q];
#pragma unroll
    for (int i = 0; i < 4; i++) acc[i][q] = bv;
  }
#pragma unroll
  for (int ky = 0; ky < 3; ky++) {
    int hy = h + ky - 1;
    if ((unsigned)hy >= 64u) continue;
    float row[6][8];
#pragma unroll
    for (int j = 0; j < 6; j++) {
      int wx = w0 + j - 1;
      bool valid = (unsigned)wx < 64u;
      int wxc = valid ? wx : 0;
      bf16x8 iv = *(const bf16x8*)(qv + (base + hy * 64 + wxc) * 512 + 256 + c0);
#pragma unroll
      for (int q = 0; q < 8; q++) row[j][q] = valid ? hswish((float)iv[q]) : 0.f;
    }
#pragma unroll
    for (int kx = 0; kx < 3; kx++) {
      bf16x8 wv = *(const bf16x8*)(wt + (ky * 3 + kx) * 256 + c0);
      float wf[8];
#pragma unroll
      for (int q = 0; q < 8; q++) wf[q] = (float)wv[q];
#pragma unroll
      for (int i = 0; i < 4; i++)
#pragma unroll
        for (int q = 0; q < 8; q++) acc[i][q] += row[i + kx][q] * wf[q];
    }
  }
#pragma unroll
  for (int i = 0; i < 4; i++) {
    long t = base + h * 64 + w0 + i;
    bf16x8 o;
#pragma unroll
    for (int q = 0; q < 8; q++) o[q] = (bf16)acc[i][q];
    *(bf16x8*)(vconv + t * 256 + c0) = o;
  }
}

// ---------------- cross-window attention (8-wave blocks, r18: ~30us) ----------------
__global__ __launch_bounds__(512) void attn_kernel(const bf16* __restrict__ qv,
                                                   const bf16* __restrict__ vconv,
                                                   bf16* __restrict__ aout) {
  __shared__ __align__(16) bf16 Kl[512 * 32];
  __shared__ __align__(16) bf16 Vt[32 * 512];
  const int tid = threadIdx.x, lane = tid & 63, wid = tid >> 6;
  const int u = blockIdx.x >> 1, hf = blockIdx.x & 1;
  const int head = u & 3, g = (u >> 2) & 7, dir = (u >> 5) & 1, b = u >> 6;
  const int qch = dir * 128 + head * 32;
  const int vch = 256 + qch;
  char* KlB = (char*)Kl;
  char* VtB = (char*)Vt;

#pragma unroll
  for (int it = 0; it < 4; it++) {
    int task = it * 512 + tid;
    int t = task >> 2, cg = task & 3;
    long tk = tmap(dir, b, g, t);
    bf16x8 v = *(const bf16x8*)(qv + tk * 512 + vch + cg * 8);
    int byte = (t * 64 + cg * 16) ^ ((t & 7) << 4);
    *(bf16x8*)(KlB + byte) = v;
  }
  __syncthreads();
#pragma unroll
  for (int it = 0; it < 4; it++) {
    int task = it * 512 + tid;
    int ch = task & 31, kvb = task >> 5;
    int c = kvb >> 2, fb = kvb & 3;
    bf16 tv[8];
#pragma unroll
    for (int j = 0; j < 8; j++) {
      int kv = c * 32 + (j < 4 ? fb * 4 + j : 16 + fb * 4 + (j - 4));
      int byte = (kv * 64 + ch * 2) ^ ((kv & 7) << 4);
      tv[j] = *(const bf16*)(KlB + byte);
    }
    int wbyte = (ch * 1024 + kvb * 16) ^ ((ch & 7) << 4);
    *(bf16x8*)(VtB + wbyte) = *(bf16x8*)tv;
  }
  __syncthreads();

  const int fr = lane & 15, fkh = lane >> 4;
  const float scaleL2 = 0.17677669529663687f * 1.4426950408889634f;
  const float THR = 11.541560327111708f;
  const f32x4 zero = {0.f, 0.f, 0.f, 0.f};

  int qrowA = hf * 256 + wid * 32;
  int qrowB = qrowA + 16;
  long tqA = tmap(dir, b, g, qrowA + fr);
  long tqB = tmap(dir, b, g, qrowB + fr);
  bf16x8 qfA = *(const bf16x8*)(qv + tqA * 512 + qch + fkh * 8);
  bf16x8 qfB = *(const bf16x8*)(qv + tqB * 512 + qch + fkh * 8);
  float mA = 5.7707801635f, lA = 0.f, mB = 5.7707801635f, lB = 0.f;
  f32x4 oA0 = zero, oA1 = zero, oB0 = zero, oB1 = zero;
#pragma unroll 2
  for (int c = 0; c < 16; c++) {
    int kb0 = ((c * 32 + fr) * 64 + fkh * 16) ^ ((fr & 7) << 4);
    int kb1 = ((c * 32 + 16 + fr) * 64 + fkh * 16) ^ ((fr & 7) << 4);
    bf16x8 kf0 = *(const bf16x8*)(KlB + kb0);
    bf16x8 kf1 = *(const bf16x8*)(KlB + kb1);
    int vb = ((c * 32 + fkh * 8) * 2) ^ ((fr & 7) << 4);
    bf16x8 v0 = *(const bf16x8*)(VtB + fr * 1024 + vb);
    bf16x8 v1 = *(const bf16x8*)(VtB + (16 + fr) * 1024 + vb);
    f32x4 sA0 = mfma16(kf0, qfA, zero);
    f32x4 sA1 = mfma16(kf1, qfA, zero);
    f32x4 sB0 = mfma16(kf0, qfB, zero);
    f32x4 sB1 = mfma16(kf1, qfB, zero);
    float cmaxA = -1e30f, cmaxB = -1e30f;
#pragma unroll
    for (int r = 0; r < 4; r++) {
      sA0[r] *= scaleL2; sA1[r] *= scaleL2;
      sB0[r] *= scaleL2; sB1[r] *= scaleL2;
      cmaxA = fmaxf(cmaxA, fmaxf(sA0[r], sA1[r]));
      cmaxB = fmaxf(cmaxB, fmaxf(sB0[r], sB1[r]));
    }
    if (__any(cmaxA > mA + THR)) {
      float cm = cmaxA;
      cm = fmaxf(cm, __shfl_xor(cm, 16));
      cm = fmaxf(cm, __shfl_xor(cm, 32));
      float mn = fmaxf(mA, cm);
      float corr = exp2f(mA - mn);
      lA *= corr;
      float c0c = __shfl(corr, fkh * 4 + 0);
      float c1c = __shfl(corr, fkh * 4 + 1);
      float c2c = __shfl(corr, fkh * 4 + 2);
      float c3c = __shfl(corr, fkh * 4 + 3);
      oA0[0] *= c0c; oA0[1] *= c1c; oA0[2] *= c2c; oA0[3] *= c3c;
      oA1[0] *= c0c; oA1[1] *= c1c; oA1[2] *= c2c; oA1[3] *= c3c;
      mA = mn;
    }
    if (__any(cmaxB > mB + THR)) {
      float cm = cmaxB;
      cm = fmaxf(cm, __shfl_xor(cm, 16));
      cm = fmaxf(cm, __shfl_xor(cm, 32));
      float mn = fmaxf(mB, cm);
      float corr = exp2f(mB - mn);
      lB *= corr;
      float c0c = __shfl(corr, fkh * 4 + 0);
      float c1c = __shfl(corr, fkh * 4 + 1);
      float c2c = __shfl(corr, fkh * 4 + 2);
      float c3c = __shfl(corr, fkh * 4 + 3);
      oB0[0] *= c0c; oB0[1] *= c1c; oB0[2] *= c2c; oB0[3] *= c3c;
      oB1[0] *= c0c; oB1[1] *= c1c; oB1[2] *= c2c; oB1[3] *= c3c;
      mB = mn;
    }
    float pA0[4], pA1[4], pB0[4], pB1[4];
#pragma unroll
    for (int r = 0; r < 4; r++) {
      pA0[r] = exp2f(sA0[r] - mA);
      pA1[r] = exp2f(sA1[r] - mA);
      pB0[r] = exp2f(sB0[r] - mB);
      pB1[r] = exp2f(sB1[r] - mB);
      lA += pA0[r] + pA1[r];
      lB += pB0[r] + pB1[r];
    }
    union { unsigned u[4]; bf16x8 v8; } paA, paB;
    paA.u[0] = packbf2(pA0[0], pA0[1]);
    paA.u[1] = packbf2(pA0[2], pA0[3]);
    paA.u[2] = packbf2(pA1[0], pA1[1]);
    paA.u[3] = packbf2(pA1[2], pA1[3]);
    paB.u[0] = packbf2(pB0[0], pB0[1]);
    paB.u[1] = packbf2(pB0[2], pB0[3]);
    paB.u[2] = packbf2(pB1[0], pB1[1]);
    paB.u[3] = packbf2(pB1[2], pB1[3]);
    oA0 = mfma16(paA.v8, v0, oA0);
    oA1 = mfma16(paA.v8, v1, oA1);
    oB0 = mfma16(paB.v8, v0, oB0);
    oB1 = mfma16(paB.v8, v1, oB1);
  }
  float ltA = lA;
  ltA += __shfl_xor(ltA, 16);
  ltA += __shfl_xor(ltA, 32);
  float invA = 1.f / ltA;
  float ltB = lB;
  ltB += __shfl_xor(ltB, 16);
  ltB += __shfl_xor(ltB, 32);
  float invB = 1.f / ltB;
  float iA[4], iB[4];
#pragma unroll
  for (int r = 0; r < 4; r++) {
    iA[r] = __shfl(invA, fkh * 4 + r);
    iB[r] = __shfl(invB, fkh * 4 + r);
  }
#pragma unroll
  for (int r = 0; r < 4; r++) {
    int rowA = qrowA + fkh * 4 + r;
    long toA = tmap(dir, b, g, rowA);
    float vc0 = (float)vconv[toA * 256 + qch + fr];
    float vc1 = (float)vconv[toA * 256 + qch + 16 + fr];
    aout[toA * 256 + qch + fr] = (bf16)hswish(oA0[r] * iA[r] + vc0);
    aout[toA * 256 + qch + 16 + fr] = (bf16)hswish(oA1[r] * iA[r] + vc1);
    int rowB = qrowB + fkh * 4 + r;
    long toB = tmap(dir, b, g, rowB);
    float wc0 = (float)vconv[toB * 256 + qch + fr];
    float wc1 = (float)vconv[toB * 256 + qch + 16 + fr];
    aout[toB * 256 + qch + fr] = (bf16)hswish(oB0[r] * iB[r] + wc0);
    aout[toB * 256 + qch + 16 + fr] = (bf16)hswish(oB1[r] * iB[r] + wc1);
  }
}

// ---------------- BN final: reduce 256 slots -> scale/shift coefs ----------------
__global__ void bn_final(const float* __restrict__ part, const bf16* __restrict__ g,
                         const bf16* __restrict__ bb, float* __restrict__ coef) {
  int c = threadIdx.x;
  float s = 0.f, q = 0.f;
  for (int i = 0; i < 256; i++) { s += part[i * 256 + c]; q += part[65536 + i * 256 + c]; }
  float mu = s * (1.f / 16384.f);
  float var = q * (1.f / 16384.f) - mu * mu;
  float sc = (float)g[c] * rsqrtf(var + 1e-5f);
  coef[c] = sc;
  coef[256 + c] = (float)bb[c] - mu * sc;
}

// ---------------- x2 = BN(a2) + DES(res) + res, fused with LayerNorm2 --------------
__global__ __launch_bounds__(256) void des_combine_ln(const float* __restrict__ xf,
                                                      const bf16* __restrict__ a2,
                                                      const float* __restrict__ coef,
                                                      const bf16* __restrict__ wr,
                                                      const bf16* __restrict__ br,
                                                      const bf16* __restrict__ wl,
                                                      const bf16* __restrict__ bl,
                                                      const bf16* __restrict__ ln2w,
                                                      const bf16* __restrict__ ln2b,
                                                      bf16* __restrict__ x2,
                                                      bf16* __restrict__ xnb) {
  __shared__ float X[4][256], M1[4][256];
  __shared__ float WR[256], WL[256], BR[16], BL[16], SC[256], SH[256], W2[256], B2[256];
  int tid = threadIdx.x, lane = tid & 63, wvi = tid >> 6;
  WR[tid] = (float)wr[tid];
  WL[tid] = (float)wl[tid];
  SC[tid] = coef[tid];
  SH[tid] = coef[256 + tid];
  W2[tid] = (float)ln2w[tid];
  B2[tid] = (float)ln2b[tid];
  if (tid < 16) { BR[tid] = (float)br[tid]; BL[tid] = (float)bl[tid]; }
  long t = (long)blockIdx.x * 4 + wvi;
  f32x4 xv = *(const f32x4*)(xf + t * 256 + lane * 4);
#pragma unroll
  for (int i = 0; i < 4; i++) X[wvi][lane * 4 + i] = xv[i];
  __syncthreads();
#pragma unroll
  for (int u2 = 0; u2 < 4; u2++) {
    int e = u2 * 64 + lane, k = e >> 4, p = e & 15;
    float acc = BR[p];
#pragma unroll
    for (int p2 = 0; p2 < 16; p2++) acc += X[wvi][k * 16 + p2] * WR[p2 * 16 + p];
    M1[wvi][e] = gelu_exact(acc);
  }
  __syncthreads();
  float v4[4];
#pragma unroll
  for (int u2 = 0; u2 < 4; u2++) {
    int e = u2 * 64 + lane, k = e >> 4, p = e & 15;
    float acc = BL[k];
#pragma unroll
    for (int k2 = 0; k2 < 16; k2++) acc += M1[wvi][k2 * 16 + p] * WL[k2 * 16 + k];
    float a2v = (float)a2[t * 256 + e];
    v4[u2] = SC[e] * a2v + SH[e] + acc + X[wvi][e];
  }
  float s = v4[0] + v4[1] + v4[2] + v4[3];
#pragma unroll
  for (int m = 1; m < 64; m <<= 1) s += __shfl_xor(s, m);
  float mu = s * (1.f / 256.f);
  float q = 0.f;
#pragma unroll
  for (int i = 0; i < 4; i++) { float d = v4[i] - mu; q += d * d; }
#pragma unroll
  for (int m = 1; m < 64; m <<= 1) q += __shfl_xor(q, m);
  float r = rsqrtf(q * (1.f / 256.f) + 1e-5f);
#pragma unroll
  for (int u2 = 0; u2 < 4; u2++) {
    int e = u2 * 64 + lane;
    x2[t * 256 + e] = (bf16)v4[u2];
    xnb[t * 256 + e] = (bf16)((v4[u2] - mu) * r * W2[e] + B2[e]);
  }
}

// ---------------- MixCFN depthwise 3x3 / 5x5 + fast gelu (h-pair row reuse) --------
// grid 1024: bx -> slice(4 x 256ch) | wh(2 x 32w) | hpair(32) | b(4).
// Block computes 2 output rows; input rows shared in registers:
// loads/output-row drop 18->12 (3x3) and 40->24 (5x5).
__global__ __launch_bounds__(256) void mixconv(const bf16* __restrict__ h1,
                                               const bf16* __restrict__ wt3,
                                               const bf16* __restrict__ b3,
                                               const bf16* __restrict__ wt5,
                                               const bf16* __restrict__ b5,
                                               bf16* __restrict__ hc) {
  int bx = blockIdx.x;
  int slice = bx & 3, wh = (bx >> 2) & 1, hp = (bx >> 3) & 31, b = bx >> 8;
  int h0 = hp * 2;
  int tid = threadIdx.x;
  int c0 = slice * 256 + (tid & 31) * 8;
  int w0 = wh * 32 + (tid >> 5) * 4;
  bool five = slice >= 2;
  int cc = five ? c0 - 512 : c0;
  long base = (long)b * 4096;
  float acc[2][4][8];
  {
    const bf16* bp = (five ? b5 : b3) + cc;
#pragma unroll
    for (int q = 0; q < 8; q++) {
      float bv = (float)bp[q];
#pragma unroll
      for (int o = 0; o < 2; o++)
#pragma unroll
        for (int i = 0; i < 4; i++) acc[o][i][q] = bv;
    }
  }
  if (!five) {
    const bf16* wbase = wt3 + cc;
#pragma unroll
    for (int dy = 0; dy < 4; dy++) {       // input rows h0-1 .. h0+2
      int iy = h0 + dy - 1;
      if ((unsigned)iy >= 64u) continue;   // wave-uniform
      float row[6][8];
#pragma unroll
      for (int j = 0; j < 6; j++) {
        int wx = w0 + j - 1;
        bool valid = (unsigned)wx < 64u;
        int wxc = valid ? wx : 0;
        bf16x8 iv = *(const bf16x8*)(h1 + (base + iy * 64 + wxc) * 1024 + c0);
#pragma unroll
        for (int q = 0; q < 8; q++) row[j][q] = valid ? (float)iv[q] : 0.f;
      }
#pragma unroll
      for (int o = 0; o < 2; o++) {        // output rows h0, h0+1
        int ky = dy - 1 - o + 1;           // = dy - o; tap row index
        if (ky < 0 || ky > 2) continue;    // compile-time resolvable per (dy,o)
#pragma unroll
        for (int kx = 0; kx < 3; kx++) {
          bf16x8 wv = *(const bf16x8*)(wbase + (ky * 3 + kx) * 512);
          float wf[8];
#pragma unroll
          for (int q = 0; q < 8; q++) wf[q] = (float)wv[q];
#pragma unroll
          for (int i = 0; i < 4; i++)
#pragma unroll
            for (int q = 0; q < 8; q++) acc[o][i][q] += row[i + kx][q] * wf[q];
        }
      }
    }
  } else {
    const bf16* wbase = wt5 + cc;
#pragma unroll
    for (int dy = 0; dy < 6; dy++) {       // input rows h0-2 .. h0+3
      int iy = h0 + dy - 2;
      if ((unsigned)iy >= 64u) continue;
      float row[8][8];
#pragma unroll
      for (int j = 0; j < 8; j++) {
        int wx = w0 + j - 2;
        bool valid = (unsigned)wx < 64u;
        int wxc = valid ? wx : 0;
        bf16x8 iv = *(const bf16x8*)(h1 + (base + iy * 64 + wxc) * 1024 + c0);
#pragma unroll
        for (int q = 0; q < 8; q++) row[j][q] = valid ? (float)iv[q] : 0.f;
      }
#pragma unroll
      for (int o = 0; o < 2; o++) {
        int ky = dy - o;                   // tap row (dy-2) - o + 2
        if (ky < 0 || ky > 4) continue;
#pragma unroll
        for (int kx = 0; kx < 5; kx++) {
          bf16x8 wv = *(const bf16x8*)(wbase + (ky * 5 + kx) * 512);
          float wf[8];
#pragma unroll
          for (int q = 0; q < 8; q++) wf[q] = (float)wv[q];
#pragma unroll
          for (int i = 0; i < 4; i++)
#pragma unroll
            for (int q = 0; q < 8; q++) acc[o][i][q] += row[i + kx][q] * wf[q];
        }
      }
    }
  }
#pragma unroll
  for (int o = 0; o < 2; o++) {
#pragma unroll
    for (int i = 0; i < 4; i++) {
      long t = base + (h0 + o) * 64 + w0 + i;
      bf16x8 ov;
#pragma unroll
      for (int q = 0; q < 8; q++) ov[q] = (bf16)gelu_fast(acc[o][i][q]);
      *(bf16x8*)(hc + t * 1024 + c0) = ov;
    }
  }
}

extern "C" void kernel_launch(void* const* d_in, const int* in_sizes, int n_in,
                              void* d_out, int out_size, void* d_ws, size_t ws_size,
                              hipStream_t stream) {
  if (ws_size < 92274688ull) return;

  char* ws = (char*)d_ws;
  float* bncoef = (float*)(ws + 256);   // 512 f32
  char* Dc = ws + 4096;
  auto alloc = [&](size_t bytes) { bf16* p = (bf16*)Dc; Dc += (bytes + 255) & ~(size_t)255; return p; };
  bf16* cWqkvT  = alloc(262144);
  bf16* cWoutT  = alloc(131072);
  bf16* cfc1T   = alloc(524288);
  bf16* cfc2T   = alloc(524288);
  bf16* cconvp  = alloc(4608);
  bf16* cwt3    = alloc(9216);
  bf16* cwt5    = alloc(25600);
  bf16* cln1w   = alloc(512);
  bf16* cln1b   = alloc(512);
  bf16* cbqkv   = alloc(1024);
  bf16* cconvpb = alloc(512);
  bf16* cbout   = alloc(512);
  bf16* cbng    = alloc(512);
  bf16* cbnb    = alloc(512);
  bf16* cdwr    = alloc(512);
  bf16* cdbr    = alloc(32);
  bf16* cdwl    = alloc(512);
  bf16* cdbl    = alloc(32);
  bf16* cln2w   = alloc(512);
  bf16* cln2b   = alloc(512);
  bf16* cfc1b   = alloc(2048);
  bf16* cm3b    = alloc(1024);
  bf16* cm5b    = alloc(1024);
  bf16* cfc2b   = alloc(512);
  bf16* qv    = (bf16*)(ws + 16777216);
  bf16* vconv = (bf16*)(ws + 33554432);
  bf16* attn  = (bf16*)(ws + 41943040);
  bf16* h1    = (bf16*)(ws + 16777216);
  bf16* xnb     = (bf16*)(ws + 50331648);
  bf16* a2      = (bf16*)(ws + 58720256);
  float* bnpart = (float*)(ws + 67108864);
  bf16* hc      = (bf16*)(ws + 50331648);
  bf16* x2 = (bf16*)(ws + 83886080);

  ConvArgs ca;
  const int srcIdx[24] = {5, 9, 19, 25, 7, 21, 23, 3, 4, 6, 8, 10, 11, 12,
                          13, 14, 15, 16, 17, 18, 20, 22, 24, 26};
  bf16* dsts[24] = {cWqkvT, cWoutT, cfc1T, cfc2T, cconvp, cwt3, cwt5, cln1w, cln1b,
                    cbqkv, cconvpb, cbout, cbng, cbnb, cdwr, cdbr, cdwl, cdbl,
                    cln2w, cln2b, cfc1b, cm3b, cm5b, cfc2b};
  for (int i = 0; i < 24; i++) { ca.s[i] = (const float*)d_in[srcIdx[i]]; ca.d[i] = dsts[i]; }
  convert_w<<<2916, 256, 0, stream>>>(ca);
  convx_ln<<<4096, 256, 0, stream>>>((const float*)d_in[0], cln1w, cln1b, xnb);

  gemm_bt<<<dim3(128, 4), 256, 0, stream>>>(xnb, cWqkvT, cbqkv, nullptr, qv, nullptr, nullptr, 16384, 512, 256);
  dwconv_v<<<512, 256, 0, stream>>>(qv, cconvp, cconvpb, vconv);
  attn_kernel<<<512, 512, 0, stream>>>(qv, vconv, attn);
  gemm_bt<<<dim3(128, 2), 256, 0, stream>>>(attn, cWoutT, cbout, nullptr, a2, nullptr, bnpart, 16384, 256, 256);
  bn_final<<<1, 256, 0, stream>>>(bnpart, cbng, cbnb, bncoef);
  des_combine_ln<<<4096, 256, 0, stream>>>((const float*)d_in[0], a2, bncoef, cdwr, cdbr, cdwl, cdbl,
                                           cln2w, cln2b, x2, xnb);
  gemm_bt<<<dim3(128, 8), 256, 0, stream>>>(xnb, cfc1T, cfc1b, nullptr, h1, nullptr, nullptr, 16384, 1024, 256);
  mixconv<<<1024, 256, 0, stream>>>(h1, cwt3, cm3b, cwt5, cm5b, hc);
  gemm_bt<<<dim3(128, 2), 256, 0, stream>>>(hc, cfc2T, cfc2b, x2, nullptr, (float*)d_out, nullptr, 16384, 256, 1024);
}

// Round 21
// 208.029 us; speedup vs baseline: 1.0154x; 1.0154x over previous
//
#include <hip/hip_runtime.h>
#include <hip/hip_bf16.h>

typedef __bf16 bf16;
typedef __bf16 bf16x8 __attribute__((ext_vector_type(8)));
typedef __bf16 bf16x4 __attribute__((ext_vector_type(4)));
typedef float f32x4 __attribute__((ext_vector_type(4)));

#define DEVFN static __device__ __forceinline__

DEVFN f32x4 mfma16(bf16x8 a, bf16x8 b, f32x4 c) {
  return __builtin_amdgcn_mfma_f32_16x16x32_bf16(a, b, c, 0, 0, 0);
}

DEVFN float hswish(float x) { return x * fminf(fmaxf(x + 3.f, 0.f), 6.f) * (1.f / 6.f); }
DEVFN float gelu_exact(float x) { return 0.5f * x * (1.f + erff(x * 0.70710678118654752f)); }
DEVFN float gelu_fast(float x) {
  float x2 = x * x;
  float w = -x * (2.3022227f + 0.10295342f * x2);
  float e = __builtin_amdgcn_exp2f(w);
  return x * __builtin_amdgcn_rcpf(1.f + e);
}

DEVFN unsigned packbf2(float lo, float hi) {
  union { bf16 h; unsigned short u; } a, b;
  a.h = (bf16)lo; b.h = (bf16)hi;
  return (unsigned)a.u | ((unsigned)b.u << 16);
}

// async global->LDS, 16B/lane: dest = wave-uniform base + lane*16.
DEVFN void async16(const void* g, void* l) {
  typedef __attribute__((address_space(3))) unsigned int lds_u32;
  typedef const __attribute__((address_space(1))) unsigned int glb_u32;
  __builtin_amdgcn_global_load_lds((glb_u32*)g, (lds_u32*)l, 16, 0, 0);
}

DEVFN int tmap(int dir, int b, int g, int m) {
  return dir == 0 ? (b * 4096 + g * 512 + m)
                  : (b * 4096 + (m & 63) * 64 + g * 8 + (m >> 6));
}

// ---------------- fused convert+LayerNorm1: f32 x -> cx (bf16) + xnb (LN out) -------
__global__ __launch_bounds__(256) void convx_ln(const float* __restrict__ src,
                                                const bf16* __restrict__ w,
                                                const bf16* __restrict__ b,
                                                bf16* __restrict__ cx,
                                                bf16* __restrict__ xnb) {
  int tid = threadIdx.x, lane = tid & 63, wv = tid >> 6;
  long row = (long)blockIdx.x * 4 + wv;
  f32x4 xv = *(const f32x4*)(src + row * 256 + lane * 4);
  bf16x4 cxo;
#pragma unroll
  for (int i = 0; i < 4; i++) cxo[i] = (bf16)xv[i];
  *(bf16x4*)(cx + row * 256 + lane * 4) = cxo;
  float s = xv[0] + xv[1] + xv[2] + xv[3];
#pragma unroll
  for (int m = 1; m < 64; m <<= 1) s += __shfl_xor(s, m);
  float mu = s * (1.f / 256.f);
  float q = 0.f;
#pragma unroll
  for (int i = 0; i < 4; i++) { float d = xv[i] - mu; q += d * d; }
#pragma unroll
  for (int m = 1; m < 64; m <<= 1) q += __shfl_xor(q, m);
  float r = rsqrtf(q * (1.f / 256.f) + 1e-5f);
  bf16x4 wv4 = *(const bf16x4*)(w + lane * 4);
  bf16x4 bv4 = *(const bf16x4*)(b + lane * 4);
  bf16x4 o;
#pragma unroll
  for (int i = 0; i < 4; i++) o[i] = (bf16)((xv[i] - mu) * r * (float)wv4[i] + (float)bv4[i]);
  *(bf16x4*)(xnb + row * 256 + lane * 4) = o;
}

// ---------------- convert all other inputs (f32 -> bf16, table-driven) ----------
struct ConvArgs { const float* s[24]; bf16* d[24]; };

__global__ __launch_bounds__(256) void convert_w(ConvArgs a) {
  static const int cum[25] = {0, 131072, 196608, 458752, 720896, 723200, 727808, 740608,
                              740864, 741120, 741632, 741888, 742144, 742400, 742656,
                              742912, 742928, 743184, 743200, 743456, 743712, 744736,
                              745248, 745760, 746016};
  static const int Kt[7] = {256, 256, 256, 1024, 256, 512, 512};
  static const int Nt[7] = {512, 256, 1024, 256, 9, 9, 25};
  int g = blockIdx.x * 256 + threadIdx.x;
  if (g >= 746016) return;
  int e = 0;
  while (g >= cum[e + 1]) e++;
  int i = g - cum[e];
  float v = a.s[e][i];
  int di = i;
  if (e < 7) di = (i % Nt[e]) * Kt[e] + i / Nt[e];
  a.d[e][di] = (bf16)v;
}

// ---------------- GEMM: C[MxN] = A[MxK] @ BT[NxK]^T + bias (+resid) ----------------
__global__ __launch_bounds__(256) void gemm_bt(const bf16* __restrict__ A,
                                               const bf16* __restrict__ BT,
                                               const bf16* __restrict__ bias,
                                               const bf16* __restrict__ resid,
                                               bf16* __restrict__ C,
                                               float* __restrict__ Cf,
                                               float* __restrict__ bnp,
                                               int M, int N, int K) {
  __shared__ __align__(16) bf16 Asl[2][128 * 32];
  __shared__ __align__(16) bf16 Bsl[2][128 * 32];
  const int tid = threadIdx.x;
  const int lane = tid & 63, wid = tid >> 6;
  const int rowBase = blockIdx.x * 128, colBase = blockIdx.y * 128;
  f32x4 acc[4][4] = {};
  const int e0 = wid * 1024 + lane * 8;
  const int e1 = e0 + 512;
  const int r0 = e0 >> 5, c0 = e0 & 31;
  const int r1 = e1 >> 5, c1 = e1 & 31;
  const bf16* Ab0 = A + (long)(rowBase + r0) * K + c0;
  const bf16* Ab1 = A + (long)(rowBase + r1) * K + c1;
  const bf16* Bb0 = BT + (long)(colBase + r0) * K + c0;
  const bf16* Bb1 = BT + (long)(colBase + r1) * K + c1;
  const int wr = (wid >> 1) * 64, wc = (wid & 1) * 64;
  const int fr = lane & 15, fk = (lane >> 4) * 8;
  const int nIt = K >> 5;
  async16(Ab0, &Asl[0][wid * 1024]);
  async16(Ab1, &Asl[0][wid * 1024 + 512]);
  async16(Bb0, &Bsl[0][wid * 1024]);
  async16(Bb1, &Bsl[0][wid * 1024 + 512]);
  for (int it = 0; it < nIt; ++it) {
    const int cur = it & 1;
    __syncthreads();
    if (it + 1 < nIt) {
      const int nxt = cur ^ 1;
      const int k1 = (it + 1) << 5;
      async16(Ab0 + k1, &Asl[nxt][wid * 1024]);
      async16(Ab1 + k1, &Asl[nxt][wid * 1024 + 512]);
      async16(Bb0 + k1, &Bsl[nxt][wid * 1024]);
      async16(Bb1 + k1, &Bsl[nxt][wid * 1024 + 512]);
    }
    bf16x8 af[4], bfv[4];
#pragma unroll
    for (int m = 0; m < 4; m++) af[m] = *(const bf16x8*)&Asl[cur][(wr + m * 16 + fr) * 32 + fk];
#pragma unroll
    for (int n = 0; n < 4; n++) bfv[n] = *(const bf16x8*)&Bsl[cur][(wc + n * 16 + fr) * 32 + fk];
#pragma unroll
    for (int m = 0; m < 4; m++)
#pragma unroll
      for (int n = 0; n < 4; n++) acc[m][n] = mfma16(af[m], bfv[n], acc[m][n]);
  }
  float cs[4] = {}, cq[4] = {};
#pragma unroll
  for (int m = 0; m < 4; m++) {
#pragma unroll
    for (int r = 0; r < 4; r++) {
      int row = rowBase + wr + m * 16 + (lane >> 4) * 4 + r;
#pragma unroll
      for (int n = 0; n < 4; n++) {
        int col = colBase + wc + n * 16 + fr;
        float v = acc[m][n][r] + (float)bias[col];
        if (resid) v += (float)resid[(long)row * N + col];
        if (bnp) { cs[n] += v; cq[n] += v * v; }
        if (Cf) Cf[(long)row * N + col] = v;
        else C[(long)row * N + col] = (bf16)v;
      }
    }
  }
  if (bnp) {
#pragma unroll
    for (int n = 0; n < 4; n++) {
      float s = cs[n], q = cq[n];
      s += __shfl_xor(s, 16); s += __shfl_xor(s, 32);
      q += __shfl_xor(q, 16); q += __shfl_xor(q, 32);
      if ((lane >> 4) == 0) {
        int slot = blockIdx.x * 2 + (wid >> 1);
        int gcol = colBase + wc + n * 16 + fr;
        bnp[slot * 256 + gcol] = s;
        bnp[65536 + slot * 256 + gcol] = q;
      }
    }
  }
}

// ---------------- depthwise 3x3 on hardswish(v), row-sliding channel-last ----------
__global__ __launch_bounds__(256) void dwconv_v(const bf16* __restrict__ qv,
                                                const bf16* __restrict__ wt,
                                                const bf16* __restrict__ cb,
                                                bf16* __restrict__ vconv) {
  int bx = blockIdx.x;
  int wh = bx & 1, h = (bx >> 1) & 63, b = bx >> 7;
  int tid = threadIdx.x;
  int c0 = (tid & 31) * 8;
  int w0 = wh * 32 + (tid >> 5) * 4;
  long base = (long)b * 4096;
  float acc[4][8];
#pragma unroll
  for (int q = 0; q < 8; q++) {
    float bv = (float)cb[c0 + q];
#pragma unroll
    for (int i = 0; i < 4; i++) acc[i][q] = bv;
  }
#pragma unroll
  for (int ky = 0; ky < 3; ky++) {
    int hy = h + ky - 1;
    if ((unsigned)hy >= 64u) continue;
    float row[6][8];
#pragma unroll
    for (int j = 0; j < 6; j++) {
      int wx = w0 + j - 1;
      bool valid = (unsigned)wx < 64u;
      int wxc = valid ? wx : 0;
      bf16x8 iv = *(const bf16x8*)(qv + (base + hy * 64 + wxc) * 512 + 256 + c0);
#pragma unroll
      for (int q = 0; q < 8; q++) row[j][q] = valid ? hswish((float)iv[q]) : 0.f;
    }
#pragma unroll
    for (int kx = 0; kx < 3; kx++) {
      bf16x8 wv = *(const bf16x8*)(wt + (ky * 3 + kx) * 256 + c0);
      float wf[8];
#pragma unroll
      for (int q = 0; q < 8; q++) wf[q] = (float)wv[q];
#pragma unroll
      for (int i = 0; i < 4; i++)
#pragma unroll
        for (int q = 0; q < 8; q++) acc[i][q] += row[i + kx][q] * wf[q];
    }
  }
#pragma unroll
  for (int i = 0; i < 4; i++) {
    long t = base + h * 64 + w0 + i;
    bf16x8 o;
#pragma unroll
    for (int q = 0; q < 8; q++) o[q] = (bf16)acc[i][q];
    *(bf16x8*)(vconv + t * 256 + c0) = o;
  }
}

// ---------------- cross-window attention (8-wave blocks, r18: ~30us) ----------------
__global__ __launch_bounds__(512) void attn_kernel(const bf16* __restrict__ qv,
                                                   const bf16* __restrict__ vconv,
                                                   bf16* __restrict__ aout) {
  __shared__ __align__(16) bf16 Kl[512 * 32];
  __shared__ __align__(16) bf16 Vt[32 * 512];
  const int tid = threadIdx.x, lane = tid & 63, wid = tid >> 6;
  const int u = blockIdx.x >> 1, hf = blockIdx.x & 1;
  const int head = u & 3, g = (u >> 2) & 7, dir = (u >> 5) & 1, b = u >> 6;
  const int qch = dir * 128 + head * 32;
  const int vch = 256 + qch;
  char* KlB = (char*)Kl;
  char* VtB = (char*)Vt;

#pragma unroll
  for (int it = 0; it < 4; it++) {
    int task = it * 512 + tid;
    int t = task >> 2, cg = task & 3;
    long tk = tmap(dir, b, g, t);
    bf16x8 v = *(const bf16x8*)(qv + tk * 512 + vch + cg * 8);
    int byte = (t * 64 + cg * 16) ^ ((t & 7) << 4);
    *(bf16x8*)(KlB + byte) = v;
  }
  __syncthreads();
#pragma unroll
  for (int it = 0; it < 4; it++) {
    int task = it * 512 + tid;
    int ch = task & 31, kvb = task >> 5;
    int c = kvb >> 2, fb = kvb & 3;
    bf16 tv[8];
#pragma unroll
    for (int j = 0; j < 8; j++) {
      int kv = c * 32 + (j < 4 ? fb * 4 + j : 16 + fb * 4 + (j - 4));
      int byte = (kv * 64 + ch * 2) ^ ((kv & 7) << 4);
      tv[j] = *(const bf16*)(KlB + byte);
    }
    int wbyte = (ch * 1024 + kvb * 16) ^ ((ch & 7) << 4);
    *(bf16x8*)(VtB + wbyte) = *(bf16x8*)tv;
  }
  __syncthreads();

  const int fr = lane & 15, fkh = lane >> 4;
  const float scaleL2 = 0.17677669529663687f * 1.4426950408889634f;
  const float THR = 11.541560327111708f;
  const f32x4 zero = {0.f, 0.f, 0.f, 0.f};

  int qrowA = hf * 256 + wid * 32;
  int qrowB = qrowA + 16;
  long tqA = tmap(dir, b, g, qrowA + fr);
  long tqB = tmap(dir, b, g, qrowB + fr);
  bf16x8 qfA = *(const bf16x8*)(qv + tqA * 512 + qch + fkh * 8);
  bf16x8 qfB = *(const bf16x8*)(qv + tqB * 512 + qch + fkh * 8);
  float mA = 5.7707801635f, lA = 0.f, mB = 5.7707801635f, lB = 0.f;
  f32x4 oA0 = zero, oA1 = zero, oB0 = zero, oB1 = zero;
#pragma unroll 2
  for (int c = 0; c < 16; c++) {
    int kb0 = ((c * 32 + fr) * 64 + fkh * 16) ^ ((fr & 7) << 4);
    int kb1 = ((c * 32 + 16 + fr) * 64 + fkh * 16) ^ ((fr & 7) << 4);
    bf16x8 kf0 = *(const bf16x8*)(KlB + kb0);
    bf16x8 kf1 = *(const bf16x8*)(KlB + kb1);
    int vb = ((c * 32 + fkh * 8) * 2) ^ ((fr & 7) << 4);
    bf16x8 v0 = *(const bf16x8*)(VtB + fr * 1024 + vb);
    bf16x8 v1 = *(const bf16x8*)(VtB + (16 + fr) * 1024 + vb);
    f32x4 sA0 = mfma16(kf0, qfA, zero);
    f32x4 sA1 = mfma16(kf1, qfA, zero);
    f32x4 sB0 = mfma16(kf0, qfB, zero);
    f32x4 sB1 = mfma16(kf1, qfB, zero);
    float cmaxA = -1e30f, cmaxB = -1e30f;
#pragma unroll
    for (int r = 0; r < 4; r++) {
      sA0[r] *= scaleL2; sA1[r] *= scaleL2;
      sB0[r] *= scaleL2; sB1[r] *= scaleL2;
      cmaxA = fmaxf(cmaxA, fmaxf(sA0[r], sA1[r]));
      cmaxB = fmaxf(cmaxB, fmaxf(sB0[r], sB1[r]));
    }
    if (__any(cmaxA > mA + THR)) {
      float cm = cmaxA;
      cm = fmaxf(cm, __shfl_xor(cm, 16));
      cm = fmaxf(cm, __shfl_xor(cm, 32));
      float mn = fmaxf(mA, cm);
      float corr = exp2f(mA - mn);
      lA *= corr;
      float c0c = __shfl(corr, fkh * 4 + 0);
      float c1c = __shfl(corr, fkh * 4 + 1);
      float c2c = __shfl(corr, fkh * 4 + 2);
      float c3c = __shfl(corr, fkh * 4 + 3);
      oA0[0] *= c0c; oA0[1] *= c1c; oA0[2] *= c2c; oA0[3] *= c3c;
      oA1[0] *= c0c; oA1[1] *= c1c; oA1[2] *= c2c; oA1[3] *= c3c;
      mA = mn;
    }
    if (__any(cmaxB > mB + THR)) {
      float cm = cmaxB;
      cm = fmaxf(cm, __shfl_xor(cm, 16));
      cm = fmaxf(cm, __shfl_xor(cm, 32));
      float mn = fmaxf(mB, cm);
      float corr = exp2f(mB - mn);
      lB *= corr;
      float c0c = __shfl(corr, fkh * 4 + 0);
      float c1c = __shfl(corr, fkh * 4 + 1);
      float c2c = __shfl(corr, fkh * 4 + 2);
      float c3c = __shfl(corr, fkh * 4 + 3);
      oB0[0] *= c0c; oB0[1] *= c1c; oB0[2] *= c2c; oB0[3] *= c3c;
      oB1[0] *= c0c; oB1[1] *= c1c; oB1[2] *= c2c; oB1[3] *= c3c;
      mB = mn;
    }
    float pA0[4], pA1[4], pB0[4], pB1[4];
#pragma unroll
    for (int r = 0; r < 4; r++) {
      pA0[r] = exp2f(sA0[r] - mA);
      pA1[r] = exp2f(sA1[r] - mA);
      pB0[r] = exp2f(sB0[r] - mB);
      pB1[r] = exp2f(sB1[r] - mB);
      lA += pA0[r] + pA1[r];
      lB += pB0[r] + pB1[r];
    }
    union { unsigned u[4]; bf16x8 v8; } paA, paB;
    paA.u[0] = packbf2(pA0[0], pA0[1]);
    paA.u[1] = packbf2(pA0[2], pA0[3]);
    paA.u[2] = packbf2(pA1[0], pA1[1]);
    paA.u[3] = packbf2(pA1[2], pA1[3]);
    paB.u[0] = packbf2(pB0[0], pB0[1]);
    paB.u[1] = packbf2(pB0[2], pB0[3]);
    paB.u[2] = packbf2(pB1[0], pB1[1]);
    paB.u[3] = packbf2(pB1[2], pB1[3]);
    oA0 = mfma16(paA.v8, v0, oA0);
    oA1 = mfma16(paA.v8, v1, oA1);
    oB0 = mfma16(paB.v8, v0, oB0);
    oB1 = mfma16(paB.v8, v1, oB1);
  }
  float ltA = lA;
  ltA += __shfl_xor(ltA, 16);
  ltA += __shfl_xor(ltA, 32);
  float invA = 1.f / ltA;
  float ltB = lB;
  ltB += __shfl_xor(ltB, 16);
  ltB += __shfl_xor(ltB, 32);
  float invB = 1.f / ltB;
  float iA[4], iB[4];
#pragma unroll
  for (int r = 0; r < 4; r++) {
    iA[r] = __shfl(invA, fkh * 4 + r);
    iB[r] = __shfl(invB, fkh * 4 + r);
  }
#pragma unroll
  for (int r = 0; r < 4; r++) {
    int rowA = qrowA + fkh * 4 + r;
    long toA = tmap(dir, b, g, rowA);
    float vc0 = (float)vconv[toA * 256 + qch + fr];
    float vc1 = (float)vconv[toA * 256 + qch + 16 + fr];
    aout[toA * 256 + qch + fr] = (bf16)hswish(oA0[r] * iA[r] + vc0);
    aout[toA * 256 + qch + 16 + fr] = (bf16)hswish(oA1[r] * iA[r] + vc1);
    int rowB = qrowB + fkh * 4 + r;
    long toB = tmap(dir, b, g, rowB);
    float wc0 = (float)vconv[toB * 256 + qch + fr];
    float wc1 = (float)vconv[toB * 256 + qch + 16 + fr];
    aout[toB * 256 + qch + fr] = (bf16)hswish(oB0[r] * iB[r] + wc0);
    aout[toB * 256 + qch + 16 + fr] = (bf16)hswish(oB1[r] * iB[r] + wc1);
  }
}

// ---------------- BN final: reduce 256 slots -> scale/shift coefs ----------------
__global__ void bn_final(const float* __restrict__ part, const bf16* __restrict__ g,
                         const bf16* __restrict__ bb, float* __restrict__ coef) {
  int c = threadIdx.x;
  float s = 0.f, q = 0.f;
  for (int i = 0; i < 256; i++) { s += part[i * 256 + c]; q += part[65536 + i * 256 + c]; }
  float mu = s * (1.f / 16384.f);
  float var = q * (1.f / 16384.f) - mu * mu;
  float sc = (float)g[c] * rsqrtf(var + 1e-5f);
  coef[c] = sc;
  coef[256 + c] = (float)bb[c] - mu * sc;
}

// ---------------- x2 = BN(a2) + DES(res) + res, fused with LayerNorm2 --------------
// Residual read from bf16 cx (8MB) instead of f32 x (64MB); r14-proven accuracy.
__global__ __launch_bounds__(256) void des_combine_ln(const bf16* __restrict__ x,
                                                      const bf16* __restrict__ a2,
                                                      const float* __restrict__ coef,
                                                      const bf16* __restrict__ wr,
                                                      const bf16* __restrict__ br,
                                                      const bf16* __restrict__ wl,
                                                      const bf16* __restrict__ bl,
                                                      const bf16* __restrict__ ln2w,
                                                      const bf16* __restrict__ ln2b,
                                                      bf16* __restrict__ x2,
                                                      bf16* __restrict__ xnb) {
  __shared__ float X[4][256], M1[4][256];
  __shared__ float WR[256], WL[256], BR[16], BL[16], SC[256], SH[256], W2[256], B2[256];
  int tid = threadIdx.x, lane = tid & 63, wvi = tid >> 6;
  WR[tid] = (float)wr[tid];
  WL[tid] = (float)wl[tid];
  SC[tid] = coef[tid];
  SH[tid] = coef[256 + tid];
  W2[tid] = (float)ln2w[tid];
  B2[tid] = (float)ln2b[tid];
  if (tid < 16) { BR[tid] = (float)br[tid]; BL[tid] = (float)bl[tid]; }
  long t = (long)blockIdx.x * 4 + wvi;
  bf16x4 xv = *(const bf16x4*)(x + t * 256 + lane * 4);
#pragma unroll
  for (int i = 0; i < 4; i++) X[wvi][lane * 4 + i] = (float)xv[i];
  __syncthreads();
#pragma unroll
  for (int u2 = 0; u2 < 4; u2++) {
    int e = u2 * 64 + lane, k = e >> 4, p = e & 15;
    float acc = BR[p];
#pragma unroll
    for (int p2 = 0; p2 < 16; p2++) acc += X[wvi][k * 16 + p2] * WR[p2 * 16 + p];
    M1[wvi][e] = gelu_exact(acc);
  }
  __syncthreads();
  float v4[4];
#pragma unroll
  for (int u2 = 0; u2 < 4; u2++) {
    int e = u2 * 64 + lane, k = e >> 4, p = e & 15;
    float acc = BL[k];
#pragma unroll
    for (int k2 = 0; k2 < 16; k2++) acc += M1[wvi][k2 * 16 + p] * WL[k2 * 16 + k];
    float a2v = (float)a2[t * 256 + e];
    v4[u2] = SC[e] * a2v + SH[e] + acc + X[wvi][e];
  }
  float s = v4[0] + v4[1] + v4[2] + v4[3];
#pragma unroll
  for (int m = 1; m < 64; m <<= 1) s += __shfl_xor(s, m);
  float mu = s * (1.f / 256.f);
  float q = 0.f;
#pragma unroll
  for (int i = 0; i < 4; i++) { float d = v4[i] - mu; q += d * d; }
#pragma unroll
  for (int m = 1; m < 64; m <<= 1) q += __shfl_xor(q, m);
  float r = rsqrtf(q * (1.f / 256.f) + 1e-5f);
#pragma unroll
  for (int u2 = 0; u2 < 4; u2++) {
    int e = u2 * 64 + lane;
    x2[t * 256 + e] = (bf16)v4[u2];
    xnb[t * 256 + e] = (bf16)((v4[u2] - mu) * r * W2[e] + B2[e]);
  }
}

// ---------------- MixCFN depthwise 3x3 / 5x5 + fast gelu (row-sliding, r17) --------
__global__ __launch_bounds__(256) void mixconv(const bf16* __restrict__ h1,
                                               const bf16* __restrict__ wt3,
                                               const bf16* __restrict__ b3,
                                               const bf16* __restrict__ wt5,
                                               const bf16* __restrict__ b5,
                                               bf16* __restrict__ hc) {
  int bx = blockIdx.x;
  int slice = bx & 3, wh = (bx >> 2) & 1, h = (bx >> 3) & 63, b = bx >> 9;
  int tid = threadIdx.x;
  int c0 = slice * 256 + (tid & 31) * 8;
  int w0 = wh * 32 + (tid >> 5) * 4;
  bool five = slice >= 2;
  int cc = five ? c0 - 512 : c0;
  long base = (long)b * 4096;
  float acc[4][8];
  {
    const bf16* bp = (five ? b5 : b3) + cc;
#pragma unroll
    for (int q = 0; q < 8; q++) {
      float bv = (float)bp[q];
#pragma unroll
      for (int i = 0; i < 4; i++) acc[i][q] = bv;
    }
  }
  if (!five) {
    const bf16* wbase = wt3 + cc;
#pragma unroll
    for (int ky = 0; ky < 3; ky++) {
      int hy = h + ky - 1;
      if ((unsigned)hy >= 64u) continue;
      float row[6][8];
#pragma unroll
      for (int j = 0; j < 6; j++) {
        int wx = w0 + j - 1;
        bool valid = (unsigned)wx < 64u;
        int wxc = valid ? wx : 0;
        bf16x8 iv = *(const bf16x8*)(h1 + (base + hy * 64 + wxc) * 1024 + c0);
#pragma unroll
        for (int q = 0; q < 8; q++) row[j][q] = valid ? (float)iv[q] : 0.f;
      }
#pragma unroll
      for (int kx = 0; kx < 3; kx++) {
        bf16x8 wv = *(const bf16x8*)(wbase + (ky * 3 + kx) * 512);
        float wf[8];
#pragma unroll
        for (int q = 0; q < 8; q++) wf[q] = (float)wv[q];
#pragma unroll
        for (int i = 0; i < 4; i++)
#pragma unroll
          for (int q = 0; q < 8; q++) acc[i][q] += row[i + kx][q] * wf[q];
      }
    }
  } else {
    const bf16* wbase = wt5 + cc;
#pragma unroll
    for (int ky = 0; ky < 5; ky++) {
      int hy = h + ky - 2;
      if ((unsigned)hy >= 64u) continue;
      float row[8][8];
#pragma unroll
      for (int j = 0; j < 8; j++) {
        int wx = w0 + j - 2;
        bool valid = (unsigned)wx < 64u;
        int wxc = valid ? wx : 0;
        bf16x8 iv = *(const bf16x8*)(h1 + (base + hy * 64 + wxc) * 1024 + c0);
#pragma unroll
        for (int q = 0; q < 8; q++) row[j][q] = valid ? (float)iv[q] : 0.f;
      }
#pragma unroll
      for (int kx = 0; kx < 5; kx++) {
        bf16x8 wv = *(const bf16x8*)(wbase + (ky * 5 + kx) * 512);
        float wf[8];
#pragma unroll
        for (int q = 0; q < 8; q++) wf[q] = (float)wv[q];
#pragma unroll
        for (int i = 0; i < 4; i++)
#pragma unroll
          for (int q = 0; q < 8; q++) acc[i][q] += row[i + kx][q] * wf[q];
      }
    }
  }
#pragma unroll
  for (int i = 0; i < 4; i++) {
    long t = base + h * 64 + w0 + i;
    bf16x8 o;
#pragma unroll
    for (int q = 0; q < 8; q++) o[q] = (bf16)gelu_fast(acc[i][q]);
    *(bf16x8*)(hc + t * 1024 + c0) = o;
  }
}

extern "C" void kernel_launch(void* const* d_in, const int* in_sizes, int n_in,
                              void* d_out, int out_size, void* d_ws, size_t ws_size,
                              hipStream_t stream) {
  if (ws_size < 92274688ull) return;

  char* ws = (char*)d_ws;
  float* bncoef = (float*)(ws + 256);   // 512 f32
  char* Dc = ws + 4096;
  auto alloc = [&](size_t bytes) { bf16* p = (bf16*)Dc; Dc += (bytes + 255) & ~(size_t)255; return p; };
  bf16* cx      = alloc(8388608);   // x as bf16, 16384x256
  bf16* cWqkvT  = alloc(262144);
  bf16* cWoutT  = alloc(131072);
  bf16* cfc1T   = alloc(524288);
  bf16* cfc2T   = alloc(524288);
  bf16* cconvp  = alloc(4608);
  bf16* cwt3    = alloc(9216);
  bf16* cwt5    = alloc(25600);
  bf16* cln1w   = alloc(512);
  bf16* cln1b   = alloc(512);
  bf16* cbqkv   = alloc(1024);
  bf16* cconvpb = alloc(512);
  bf16* cbout   = alloc(512);
  bf16* cbng    = alloc(512);
  bf16* cbnb    = alloc(512);
  bf16* cdwr    = alloc(512);
  bf16* cdbr    = alloc(32);
  bf16* cdwl    = alloc(512);
  bf16* cdbl    = alloc(32);
  bf16* cln2w   = alloc(512);
  bf16* cln2b   = alloc(512);
  bf16* cfc1b   = alloc(2048);
  bf16* cm3b    = alloc(1024);
  bf16* cm5b    = alloc(1024);
  bf16* cfc2b   = alloc(512);
  bf16* qv    = (bf16*)(ws + 16777216);
  bf16* vconv = (bf16*)(ws + 33554432);
  bf16* attn  = (bf16*)(ws + 41943040);
  bf16* h1    = (bf16*)(ws + 16777216);
  bf16* xnb     = (bf16*)(ws + 50331648);
  bf16* a2      = (bf16*)(ws + 58720256);
  float* bnpart = (float*)(ws + 67108864);
  bf16* hc      = (bf16*)(ws + 50331648);
  bf16* x2 = (bf16*)(ws + 83886080);

  ConvArgs ca;
  const int srcIdx[24] = {5, 9, 19, 25, 7, 21, 23, 3, 4, 6, 8, 10, 11, 12,
                          13, 14, 15, 16, 17, 18, 20, 22, 24, 26};
  bf16* dsts[24] = {cWqkvT, cWoutT, cfc1T, cfc2T, cconvp, cwt3, cwt5, cln1w, cln1b,
                    cbqkv, cconvpb, cbout, cbng, cbnb, cdwr, cdbr, cdwl, cdbl,
                    cln2w, cln2b, cfc1b, cm3b, cm5b, cfc2b};
  for (int i = 0; i < 24; i++) { ca.s[i] = (const float*)d_in[srcIdx[i]]; ca.d[i] = dsts[i]; }
  convert_w<<<2916, 256, 0, stream>>>(ca);
  convx_ln<<<4096, 256, 0, stream>>>((const float*)d_in[0], cln1w, cln1b, cx, xnb);

  gemm_bt<<<dim3(128, 4), 256, 0, stream>>>(xnb, cWqkvT, cbqkv, nullptr, qv, nullptr, nullptr, 16384, 512, 256);
  dwconv_v<<<512, 256, 0, stream>>>(qv, cconvp, cconvpb, vconv);
  attn_kernel<<<512, 512, 0, stream>>>(qv, vconv, attn);
  gemm_bt<<<dim3(128, 2), 256, 0, stream>>>(attn, cWoutT, cbout, nullptr, a2, nullptr, bnpart, 16384, 256, 256);
  bn_final<<<1, 256, 0, stream>>>(bnpart, cbng, cbnb, bncoef);
  des_combine_ln<<<4096, 256, 0, stream>>>(cx, a2, bncoef, cdwr, cdbr, cdwl, cdbl,
                                           cln2w, cln2b, x2, xnb);
  gemm_bt<<<dim3(128, 8), 256, 0, stream>>>(xnb, cfc1T, cfc1b, nullptr, h1, nullptr, nullptr, 16384, 1024, 256);
  mixconv<<<2048, 256, 0, stream>>>(h1, cwt3, cm3b, cwt5, cm5b, hc);
  gemm_bt<<<dim3(128, 2), 256, 0, stream>>>(hc, cfc2T, cfc2b, x2, nullptr, (float*)d_out, nullptr, 16384, 256, 1024);
}